// Round 1
// baseline (12.840 us; speedup 1.0000x reference)
//
#include <hip/hip_runtime.h>

// SAConv: reference's scale = sqrt(heads // COUT) = sqrt(8 // 64) = 0  (Python
// integer division) => logits == 0 => softmax uniform (1/49) => output is the
// 7x7 box-mean of v_full = hswish(grouped_1x1(pad(x), wv)). q/k/rel are dead.
//
// Fused kernel: per (b, head, 4-row tile):
//   1) stage v tile (10 x 62 x 8ch) into LDS: grouped 1x1 conv (8->8) + hswish
//   2) horizontal 7-sum into LDS (10 x 56 x 8ch)
//   3) vertical 7-sum, * (1/49), store.

namespace {
constexpr int Bn = 8, CINn = 64, Hn = 56, Wn = 56;
constexpr int HEADSn = 8, CGn = 8;      // 8 channels in & out per head
constexpr int PADn = 3;
constexpr int TH = 4;                   // output rows per block
constexpr int NTILES = Hn / TH;         // 14
constexpr int PH = TH + 6;              // 10 staged rows
constexpr int PW = Wn + 6;              // 62 staged cols
constexpr int NP = PH * PW;             // 620 staged positions
constexpr int NHS = PH * Wn;            // 560 hsum positions
constexpr int NOUT = TH * Wn;           // 224 output positions
constexpr int THREADS = 256;
}

__global__ __launch_bounds__(THREADS) void saconv_fused(
    const float* __restrict__ x, const float* __restrict__ wv,
    float* __restrict__ out)
{
    __shared__ float wvs[64];          // this head's wv[o][i]
    __shared__ float vt[NP * 8];       // staged v tile, [pos][o]
    __shared__ float hs[NHS * 8];      // horizontal 7-sums, [pos][o]

    const int bid  = blockIdx.x;
    const int tile = bid % NTILES;
    const int g    = (bid / NTILES) % HEADSn;
    const int b    = bid / (NTILES * HEADSn);
    const int h0   = tile * TH;
    const int tid  = threadIdx.x;

    if (tid < 64) wvs[tid] = wv[g * 64 + tid];
    __syncthreads();

    const float* __restrict__ xg =
        x + (size_t)(b * CINn + g * CGn) * (Hn * Wn);

    // ---- phase 1: stage v = hswish(wv . x) over padded tile ----
    for (int p = tid; p < NP; p += THREADS) {
        const int py = p / PW;
        const int px = p - py * PW;
        const int y  = h0 + py - PADn;
        const int xx = px - PADn;
        float v[8];
        if (y >= 0 && y < Hn && xx >= 0 && xx < Wn) {
            float in[8];
            #pragma unroll
            for (int i = 0; i < 8; ++i)
                in[i] = xg[i * (Hn * Wn) + y * Wn + xx];
            #pragma unroll
            for (int o = 0; o < 8; ++o) {
                float a = 0.0f;
                #pragma unroll
                for (int i = 0; i < 8; ++i)
                    a = fmaf(wvs[o * 8 + i], in[i], a);
                float t = fminf(fmaxf(a + 3.0f, 0.0f), 6.0f);
                v[o] = a * t * (1.0f / 6.0f);
            }
        } else {
            #pragma unroll
            for (int o = 0; o < 8; ++o) v[o] = 0.0f;
        }
        #pragma unroll
        for (int o = 0; o < 8; ++o) vt[p * 8 + o] = v[o];
    }
    __syncthreads();

    // ---- phase 2: horizontal 7-sum ----
    for (int p = tid; p < NHS; p += THREADS) {
        const int y  = p / Wn;
        const int xx = p - y * Wn;
        float s[8] = {0, 0, 0, 0, 0, 0, 0, 0};
        #pragma unroll
        for (int j = 0; j < 7; ++j) {
            const float* src = &vt[(y * PW + xx + j) * 8];
            #pragma unroll
            for (int o = 0; o < 8; ++o) s[o] += src[o];
        }
        #pragma unroll
        for (int o = 0; o < 8; ++o) hs[p * 8 + o] = s[o];
    }
    __syncthreads();

    // ---- phase 3: vertical 7-sum, scale by 1/49, store ----
    if (tid < NOUT) {
        const int ty = tid / Wn;
        const int tx = tid - ty * Wn;
        float s[8] = {0, 0, 0, 0, 0, 0, 0, 0};
        #pragma unroll
        for (int i = 0; i < 7; ++i) {
            const float* src = &hs[((ty + i) * Wn + tx) * 8];
            #pragma unroll
            for (int o = 0; o < 8; ++o) s[o] += src[o];
        }
        const float inv = 1.0f / 49.0f;
        float* og = out + ((size_t)(b * CINn + g * CGn) * Hn + (h0 + ty)) * Wn + tx;
        #pragma unroll
        for (int o = 0; o < 8; ++o)
            og[o * (Hn * Wn)] = s[o] * inv;
    }
}

extern "C" void kernel_launch(void* const* d_in, const int* in_sizes, int n_in,
                              void* d_out, int out_size, void* d_ws, size_t ws_size,
                              hipStream_t stream) {
    // setup_inputs order: x, wq, wk, wv, rel_h, rel_w
    const float* x  = (const float*)d_in[0];
    const float* wv = (const float*)d_in[3];
    float* out = (float*)d_out;

    dim3 grid(Bn * HEADSn * NTILES);   // 896 blocks
    saconv_fused<<<grid, THREADS, 0, stream>>>(x, wv, out);
}

// Round 3
// 11.747 us; speedup vs baseline: 1.0931x; 1.0931x over previous
//
#include <hip/hip_runtime.h>

// SAConv: reference's scale = sqrt(heads // COUT) = 0 (Python int division)
// => softmax uniform => out = 7x7 box-mean of v = hswish(grouped_1x1(pad(x), wv)).
// q/k/rel_* are dead code.
//
// R2: same separable algorithm as R1 (per (b, head, 4-row tile):
//   P1 conv+hswish -> LDS; P2 vertical sliding 7-sum; P3 horizontal sliding
//   7-sum + store), but with the two R1-novel risk items removed after the
//   post-timing divergence:
//   - weights via LDS broadcast (R0's fully-passing path), not a 64-VGPR
//     per-thread array loaded from global
//   - plane-split LDS arrays vt[g4][row][sx(x)] with a simple x+(x>>2)
//     stagger instead of the merged 2x+g4+(x>>2) single-array swizzle.
// Determinism audit: every barrier is reached by all 256 threads; every LDS
// read in P2/P3 is of a location written in the immediately prior phase;
// output writes are disjoint and cover d_out exactly once per launch.

namespace {
constexpr int Bn = 8, CINn = 64, Hn = 56, Wn = 56;
constexpr int HEADSn = 8;
constexpr int PADn = 3;
constexpr int TH = 4;                  // output rows per block
constexpr int NTILES = Hn / TH;        // 14
constexpr int PH = TH + 6;             // 10 staged conv rows
constexpr int PW = Wn + 6;             // 62 staged cols
constexpr int RS = 80;                 // row stride in float4 (sx(61)=76 < 80)
constexpr int THREADS = 256;
constexpr int NRUNS = Wn / 2;          // 28 horizontal runs of 2
}

__device__ __forceinline__ int sx(int x) { return x + (x >> 2); }
__device__ __forceinline__ float4 f4add(float4 a, float4 b) {
    return make_float4(a.x + b.x, a.y + b.y, a.z + b.z, a.w + b.w);
}
__device__ __forceinline__ float4 f4sub(float4 a, float4 b) {
    return make_float4(a.x - b.x, a.y - b.y, a.z - b.z, a.w - b.w);
}

__global__ __launch_bounds__(THREADS) void saconv_r2(
    const float* __restrict__ x, const float* __restrict__ wv,
    float* __restrict__ out)
{
    __shared__ float  wvs[64];                 // this head's wv[o][i]
    __shared__ float4 vt[2 * PH * RS];         // 25.6 KB, [g4][py][sx(px)]
    __shared__ float4 vs[2 * TH * RS];         // 10.2 KB, [g4][y][sx(x)]

    const int bid  = blockIdx.x;
    const int tile = bid % NTILES;
    const int g    = (bid / NTILES) % HEADSn;
    const int b    = bid / (NTILES * HEADSn);
    const int h0   = tile * TH;
    const int tid  = threadIdx.x;

    if (tid < 64) wvs[tid] = wv[g * 64 + tid];
    __syncthreads();

    const float* __restrict__ xg = x + (size_t)(b * CINn + g * 8) * (Hn * Wn);

    // ---- P1: conv(8->8) + hswish over padded tile ----
    for (int p = tid; p < PH * PW; p += THREADS) {
        const int py = p / PW;
        const int px = p - py * PW;
        const int y  = h0 + py - PADn;
        const int xx = px - PADn;
        float4 v0 = make_float4(0.f, 0.f, 0.f, 0.f);
        float4 v1 = v0;
        if ((unsigned)y < (unsigned)Hn && (unsigned)xx < (unsigned)Wn) {
            float in[8];
            #pragma unroll
            for (int i = 0; i < 8; ++i)
                in[i] = xg[i * (Hn * Wn) + y * Wn + xx];
            float a[8];
            #pragma unroll
            for (int o = 0; o < 8; ++o) {
                float s = 0.f;
                #pragma unroll
                for (int i = 0; i < 8; ++i)
                    s = fmaf(wvs[o * 8 + i], in[i], s);
                float t = fminf(fmaxf(s + 3.f, 0.f), 6.f);
                a[o] = s * t * (1.f / 6.f);
            }
            v0 = make_float4(a[0], a[1], a[2], a[3]);
            v1 = make_float4(a[4], a[5], a[6], a[7]);
        }
        vt[(0 * PH + py) * RS + sx(px)] = v0;
        vt[(1 * PH + py) * RS + sx(px)] = v1;
    }
    __syncthreads();

    // ---- P2: vertical 7-sum (sliding, 2 output rows per thread) ----
    // item = (yhalf, x, g4): 2 * 62 * 2 = 248 threads
    if (tid < 2 * PW * 2) {
        const int g4 = tid & 1;
        const int r  = tid >> 1;
        const int xx = r % PW;
        const int yh = r / PW;
        const int y0 = 2 * yh;
        float4 rv[8];
        #pragma unroll
        for (int j = 0; j < 8; ++j)
            rv[j] = vt[(g4 * PH + y0 + j) * RS + sx(xx)];
        float4 s = rv[0];
        #pragma unroll
        for (int j = 1; j < 7; ++j) s = f4add(s, rv[j]);
        vs[(g4 * TH + y0) * RS + sx(xx)] = s;
        s = f4add(s, f4sub(rv[7], rv[0]));
        vs[(g4 * TH + y0 + 1) * RS + sx(xx)] = s;
    }
    __syncthreads();

    // ---- P3: horizontal 7-sum (sliding run of 2) + scale + store ----
    // item = (y, run, g4): 4 * 28 * 2 = 224 threads
    if (tid < TH * NRUNS * 2) {
        const int g4  = tid & 1;
        const int r   = tid >> 1;
        const int run = r % NRUNS;
        const int y   = r / NRUNS;
        const int x0  = run * 2;
        float4 rv[8];
        #pragma unroll
        for (int j = 0; j < 8; ++j)
            rv[j] = vs[(g4 * TH + y) * RS + sx(x0 + j)];
        float4 s0 = rv[0];
        #pragma unroll
        for (int j = 1; j < 7; ++j) s0 = f4add(s0, rv[j]);
        float4 s1 = f4add(s0, f4sub(rv[7], rv[0]));
        const float inv = 1.f / 49.f;
        float* ob = out + ((size_t)(b * CINn + g * 8 + g4 * 4) * Hn + (h0 + y)) * Wn + x0;
        const int plane = Hn * Wn;
        float2 st;
        st.x = s0.x * inv; st.y = s1.x * inv; *(float2*)(ob + 0 * plane) = st;
        st.x = s0.y * inv; st.y = s1.y * inv; *(float2*)(ob + 1 * plane) = st;
        st.x = s0.z * inv; st.y = s1.z * inv; *(float2*)(ob + 2 * plane) = st;
        st.x = s0.w * inv; st.y = s1.w * inv; *(float2*)(ob + 3 * plane) = st;
    }
}

extern "C" void kernel_launch(void* const* d_in, const int* in_sizes, int n_in,
                              void* d_out, int out_size, void* d_ws, size_t ws_size,
                              hipStream_t stream) {
    // setup_inputs order: x, wq, wk, wv, rel_h, rel_w
    const float* x  = (const float*)d_in[0];
    const float* wv = (const float*)d_in[3];
    float* out = (float*)d_out;

    dim3 grid(Bn * HEADSn * NTILES);   // 896 blocks
    saconv_r2<<<grid, THREADS, 0, stream>>>(x, wv, out);
}